// Round 15
// baseline (3388.809 us; speedup 1.0000x reference)
//
#include <hip/hip_runtime.h>
#include <cstdint>
#include <cstddef>

#define HID 64
#define RPG 8           // real batch rows per block (r-slots 8..15 stay zero)
#define ROWU 144        // ushorts per h row stripe (288B): [hi 8x16B][lo 8x16B][pad 32B]
#define XSTR 68         // floats per x row: 272 B

typedef short bf16x8 __attribute__((ext_vector_type(8)));
typedef float f32x4 __attribute__((ext_vector_type(4)));
typedef float f32x2 __attribute__((ext_vector_type(2)));

__device__ __forceinline__ f32x2 c2(float v) { f32x2 r = {v, v}; return r; }

// Packed exact-erf GELU (A&S 7.1.26, max |erf err| ~1.5e-7) on two elements.
__device__ __forceinline__ f32x2 fast_gelu2(f32x2 z) {
    const f32x2 u = z * 0.70710678118654752f;
    const f32x2 a = __builtin_elementwise_abs(u);
    const f32x2 d = __builtin_elementwise_fma(c2(0.3275911f), a, c2(1.0f));
    f32x2 t;
    t.x = __builtin_amdgcn_rcpf(d.x);
    t.y = __builtin_amdgcn_rcpf(d.y);
    const f32x2 s = u * 1.20112240878645f;      // sqrt(log2 e)
    f32x2 e;
    e.x = __builtin_amdgcn_exp2f(-(s.x * s.x)); // exp(-u^2)
    e.y = __builtin_amdgcn_exp2f(-(s.y * s.y));
    f32x2 p = c2(1.061405429f);
    p = __builtin_elementwise_fma(p, t, c2(-1.453152027f));
    p = __builtin_elementwise_fma(p, t, c2( 1.421413741f));
    p = __builtin_elementwise_fma(p, t, c2(-0.284496736f));
    p = __builtin_elementwise_fma(p, t, c2( 0.254829592f));
    p = p * t;
    f32x2 er = __builtin_elementwise_fma(-p, e, c2(1.0f));
    er = __builtin_elementwise_copysign(er, u);
    const f32x2 zh = z * 0.5f;
    return __builtin_elementwise_fma(zh, er, zh);
}

__device__ __forceinline__ ushort bf16_hi(float f) {
    return (ushort)(__float_as_uint(f) >> 16);
}
__device__ __forceinline__ float bf16_f(ushort u) {
    return __uint_as_float(((unsigned)u) << 16);
}

// Pack top halves of two f32 bit-patterns into one u32: {lo16=a>>16, hi16=b>>16}.
#define PKHI(b_, a_) __builtin_amdgcn_perm((b_), (a_), 0x07060302u)

// One step, swapped form: D'[c'][r] = sum_k W^T[c'][k] h[k][r].
// A = W^T (static regs), B = h from swizzled LDS stripes (4x ds_read_b128;
// r-slots 8..15 are zero stripes -> their C columns are bias-only garbage,
// never written). Bias rides as C-in of the ac1 chain (full f32x4).
// This wave finishes ALL 4 elements of its c-quad; writes hi/lo planes as one
// ds_write_b64 each, gated to real rows. One barrier per step.
#define STEP(RA0, RA1, WHI, WLO, XB) { \
    const bf16x8 Hhi0 = *reinterpret_cast<const bf16x8*>(RA0); \
    const bf16x8 Hlo0 = *reinterpret_cast<const bf16x8*>((RA0) + 64); \
    const bf16x8 Hhi1 = *reinterpret_cast<const bf16x8*>(RA1); \
    const bf16x8 Hlo1 = *reinterpret_cast<const bf16x8*>((RA1) + 64); \
    f32x4 xb4; xb4[0] = (XB); xb4[1] = (XB); xb4[2] = (XB); xb4[3] = (XB); \
    const f32x4 ci = __builtin_elementwise_fma(xb4, winv, cbv); \
    const f32x4 zz = {0.f, 0.f, 0.f, 0.f}; \
    f32x4 ahh = __builtin_amdgcn_mfma_f32_16x16x32_bf16(Whi0, Hhi0, zz, 0, 0, 0); \
    f32x4 ac1 = __builtin_amdgcn_mfma_f32_16x16x32_bf16(Whi0, Hlo0, ci, 0, 0, 0); \
    f32x4 ac2 = __builtin_amdgcn_mfma_f32_16x16x32_bf16(Wlo0, Hhi0, zz, 0, 0, 0); \
    ahh = __builtin_amdgcn_mfma_f32_16x16x32_bf16(Whi1, Hhi1, ahh, 0, 0, 0); \
    ac1 = __builtin_amdgcn_mfma_f32_16x16x32_bf16(Whi1, Hlo1, ac1, 0, 0, 0); \
    ac2 = __builtin_amdgcn_mfma_f32_16x16x32_bf16(Wlo1, Hhi1, ac2, 0, 0, 0); \
    const f32x4 zv = (ahh + ac1) + ac2; \
    f32x2 z01; z01.x = zv[0]; z01.y = zv[1]; \
    f32x2 z23; z23.x = zv[2]; z23.y = zv[3]; \
    const f32x2 h01 = fast_gelu2(z01); \
    const f32x2 h23 = fast_gelu2(z23); \
    const unsigned hb0 = __float_as_uint(h01.x), hb1 = __float_as_uint(h01.y); \
    const unsigned hb2 = __float_as_uint(h23.x), hb3 = __float_as_uint(h23.y); \
    uint2 hpk; hpk.x = PKHI(hb1, hb0); hpk.y = PKHI(hb3, hb2); \
    const f32x2 tr01 = { __uint_as_float(hb0 & 0xffff0000u), \
                         __uint_as_float(hb1 & 0xffff0000u) }; \
    const f32x2 tr23 = { __uint_as_float(hb2 & 0xffff0000u), \
                         __uint_as_float(hb3 & 0xffff0000u) }; \
    const f32x2 l01 = h01 - tr01; \
    const f32x2 l23 = h23 - tr23; \
    uint2 lpk; \
    lpk.x = PKHI(__float_as_uint(l01.y), __float_as_uint(l01.x)); \
    lpk.y = PKHI(__float_as_uint(l23.y), __float_as_uint(l23.x)); \
    if (rr < RPG) { *(WHI) = hpk; *(WLO) = lpk; } \
    __syncthreads(); }

__global__ __launch_bounds__(256, 2)
void ssm_kernel(const float* __restrict__ x,
                const float* __restrict__ W_in,
                const float* __restrict__ b_in,
                const float* __restrict__ W_s,
                const float* __restrict__ b_s,
                const float* __restrict__ W_out,
                const float* __restrict__ b_out,
                float* __restrict__ out,
                int B, int T) {
    // h state: 16 r-slot stripes (8 real + 8 zero), XOR-swizzled 16B slots
    // (phys = s ^ (rr&7) ^ 5*(rr>>3)); ping-pong buffers.
    __shared__ ushort hlds[2][16 * ROWU];
    __shared__ float  xlds[16][XSTR];       // x[row][t_local]; rows 8..15 zero

    const int tid  = threadIdx.x;
    const int g    = tid >> 6;        // wave 0..3: owns c-tile [16g, 16g+16)
    const int lane = tid & 63;
    const int q    = lane >> 4;
    const int rr   = lane & 15;       // lane's r-slot (C col-index); <8 = real
    const int bA   = blockIdx.x * RPG;
    const int cq   = 16 * g + 4 * q;  // c-quad base this lane produces

    if (bA >= B) return;

    // A-operand = W^T tile g (static): lane rr holds W^T[c'=rr][k=8q+e].
    bf16x8 Whi0, Whi1, Wlo0, Wlo1;
    const int wcol = 16 * g + rr;
#pragma unroll
    for (int e = 0; e < 8; ++e) {
        {   const float wf = W_s[(8 * q + e) * HID + wcol];
            const ushort hi = bf16_hi(wf);
            Whi0[e] = (short)hi;
            Wlo0[e] = (short)bf16_hi(wf - bf16_f(hi)); }
        {   const float wf = W_s[(32 + 8 * q + e) * HID + wcol];
            const ushort hi = bf16_hi(wf);
            Whi1[e] = (short)hi;
            Wlo1[e] = (short)bf16_hi(wf - bf16_f(hi)); }
    }
    // Pin in VGPRs (round-1 lesson: const global loads get rematerialized).
    asm volatile("" : "+v"(Whi0), "+v"(Whi1), "+v"(Wlo0), "+v"(Wlo1));

    // Per-element input-projection constants for this lane's c-quad.
    f32x4 winv, cbv;
#pragma unroll
    for (int e = 0; e < 4; ++e) {
        winv[e] = W_in[cq + e];
        cbv[e]  = b_in[cq + e] + b_s[cq + e];
    }

    // zero h buffers and x rows (slots >= RPG stay zero forever); ordered
    // before first read by the staging barrier below.
    {
        ushort* p = &hlds[0][0];
        for (int i = tid; i < 2 * 16 * ROWU; i += 256) p[i] = 0;
        float* xp = &xlds[0][0];
        for (int i = tid; i < 16 * XSTR; i += 256) xp[i] = 0.f;
    }

    // Swizzle for this lane's r-slot.
    const int sx = (rr & 7) ^ ((rr >> 3) * 5);

    // Read addr regs: hi slot q and q^4 (lo at +64 ushorts = offset:128).
    const ushort* const rA0 = &hlds[0][rr * ROWU + 8 * (q ^ sx)];
    const ushort* const rA1 = &hlds[0][rr * ROWU + 8 * ((q ^ 4) ^ sx)];
    const ushort* const rB0 = &hlds[1][rr * ROWU + 8 * (q ^ sx)];
    const ushort* const rB1 = &hlds[1][rr * ROWU + 8 * ((q ^ 4) ^ sx)];

    // Write pointers: els cq..cq+3 live in slot cq>>3 at offset cq&7 (8B-aligned).
    const int wl = cq >> 3;
    const int win_idx = rr * ROWU + 8 * (wl ^ sx) + (cq & 7);
    uint2* const whiA = reinterpret_cast<uint2*>(&hlds[0][win_idx]);
    uint2* const wloA = reinterpret_cast<uint2*>(&hlds[0][win_idx + 64]);
    uint2* const whiB = reinterpret_cast<uint2*>(&hlds[1][win_idx]);
    uint2* const wloB = reinterpret_cast<uint2*>(&hlds[1][win_idx + 64]);

    const int nch = T >> 6;           // T multiple of 64 (8192 here)

    for (int tc = 0; tc < nch; ++tc) {
        const size_t tg = (size_t)tc * 64;
        {   // Stage x for the 8 real rows: 256 threads x 2 floats.
            const int row = tid >> 5;        // 0..7
            const int ch  = tid & 31;        // 0..31 -> 2 floats each
            const float2 xg = *reinterpret_cast<const float2*>(
                &x[(size_t)(bA + row) * (size_t)T + tg + ch * 2]);
            *reinterpret_cast<float2*>(&xlds[row][ch * 2]) = xg;
        }
        __syncthreads();

#pragma unroll 1
        for (int t4 = 0; t4 < 16; ++t4) {
            const f32x4 xq = *reinterpret_cast<const f32x4*>(&xlds[rr][t4 * 4]);
            STEP(rA0, rA1, whiB, wloB, xq[0])
            STEP(rB0, rB1, whiA, wloA, xq[1])
            STEP(rA0, rA1, whiB, wloB, xq[2])
            STEP(rB0, rB1, whiA, wloA, xq[3])
        }
    }

    // Epilogue: h final in hlds[0] (even step count). out[b] = h.W_out + b_out.
    if (g == 0) {
        const int r  = lane >> 2;     // 0..15; only r<8 real
        const int p4 = lane & 3;
        if (r < RPG) {
            const int sxr = (r & 7) ^ ((r >> 3) * 5);
            float s = 0.f;
#pragma unroll
            for (int half = 0; half < 2; ++half) {
                const int slot = 2 * p4 + half;             // logical slot
                const ushort* hp = &hlds[0][r * ROWU + 8 * (slot ^ sxr)];
                const ushort* lp = hp + 64;
#pragma unroll
                for (int j = 0; j < 8; ++j) {
                    const float hv = bf16_f(hp[j]) + bf16_f(lp[j]);
                    s = __builtin_fmaf(hv, W_out[8 * slot + j], s);
                }
            }
            s += __shfl_xor(s, 1, 64);
            s += __shfl_xor(s, 2, 64);
            if (p4 == 0) out[bA + r] = s + b_out[0];
        }
    }
}

extern "C" void kernel_launch(void* const* d_in, const int* in_sizes, int n_in,
                              void* d_out, int out_size, void* d_ws, size_t ws_size,
                              hipStream_t stream) {
    const float* x     = (const float*)d_in[0];
    const float* W_in  = (const float*)d_in[1];
    const float* b_in  = (const float*)d_in[2];
    const float* W_s   = (const float*)d_in[3];
    const float* b_s   = (const float*)d_in[4];
    const float* W_out = (const float*)d_in[5];
    const float* b_out = (const float*)d_in[6];
    float* out = (float*)d_out;

    const int B = out_size;                 // [B,1] output
    const int T = in_sizes[0] / B;          // x is [B,T,1]

    const int blocks = B / RPG;             // 512 for B=4096 -> 2 blocks/CU
    ssm_kernel<<<blocks, 256, 0, stream>>>(
        x, W_in, b_in, W_s, b_s, W_out, b_out, out, B, T);
}